// Round 11
// baseline (82.417 us; speedup 1.0000x reference)
//
#include <hip/hip_runtime.h>

#define N_NODES 8192
#define N_EDGES 16384
#define IN_CH 32
#define HID 64
#define EDGE_DIM 4
#define N_LAYERS 3
#define N_GRAPHS 256
#define BN_EPS 1e-5f

#define NT 512
#define NPB 16                  // nodes per block
#define NBLK (N_NODES / NPB)    // 512 blocks
#define ECAP 96                 // out-edges per block cap (Poisson(32): P(>96) ~ e^-41)

// Transposed small weights (built by kprep, L1-resident in hot kernels):
//   rootT4[l*1024 + k4*64 + c] = {rootW[l][(4k4+q)*64+c]}  (3072 f4 = 48 KB)
//   winT4 [k4*64 + c]          = {lin_in_W[(4k4+q)*64+c]}  (512 f4 = 8 KB)
#define RT_TOT 3072
#define WIN_TOT 512

// -------- kprep: zero aggA (2 MB) + build rootT4/winT4 --------
__global__ __launch_bounds__(256) void kprep(
        const float* __restrict__ rootW, const float* __restrict__ Win,
        float4* __restrict__ rootT4, float4* __restrict__ winT4,
        float4* __restrict__ aggA4) {
    int i = blockIdx.x * 256 + threadIdx.x;      // grid 512*256 = 131072
    aggA4[i] = make_float4(0.f, 0.f, 0.f, 0.f);  // 131072 f4 = 2 MB exactly
    if (i < RT_TOT) {
        int l = i >> 10, r = i & 1023;
        int k4 = r >> 6, cc = r & 63;
        const float* base = rootW + (size_t)l * HID * HID;
        float4 v;
        v.x = base[(4 * k4 + 0) * 64 + cc];
        v.y = base[(4 * k4 + 1) * 64 + cc];
        v.z = base[(4 * k4 + 2) * 64 + cc];
        v.w = base[(4 * k4 + 3) * 64 + cc];
        rootT4[i] = v;
    } else if (i < RT_TOT + WIN_TOT) {
        int j = i - RT_TOT;
        int k4 = j >> 6, cc = j & 63;
        float4 v;
        v.x = Win[(4 * k4 + 0) * 64 + cc];
        v.y = Win[(4 * k4 + 1) * 64 + cc];
        v.z = Win[(4 * k4 + 2) * 64 + cc];
        v.w = Win[(4 * k4 + 3) * 64 + cc];
        winT4[j] = v;
    }
}

// -------- k0: zero aggB+pooled, lin_in (winT4 from L1), ynet0 (LDS),
//          build src-buckets, scatter->aggA --------
__global__ __launch_bounds__(NT, 4) void k0(
        const float* __restrict__ x, const float* __restrict__ bin,
        const float4* __restrict__ winT4,
        const float* __restrict__ eW, const float* __restrict__ eB,   // layer 0
        const int* __restrict__ ei, const float* __restrict__ ea,
        float* __restrict__ hG, float* __restrict__ aggA,
        float* __restrict__ aggB, float* __restrict__ pooled,
        int* __restrict__ gbcnt, int2* __restrict__ gsd, float4* __restrict__ gea) {
    __shared__ float  xs[NPB * IN_CH];    //  2 KB
    __shared__ float  hs[NPB * HID];      //  4 KB
    __shared__ float  ys[NPB * 5 * HID];  // 20 KB
    __shared__ int    cntE;
    __shared__ int2   eSL[ECAP];
    __shared__ float4 eEA[ECAP];

    const int t = threadIdx.x, b = blockIdx.x, node0 = b * NPB;
    const int c = t & 63, g = t >> 6;    // wave g (0..7) owns nodes 2g, 2g+1

    // zero aggB (512 blocks x 1024 f32 = 2MB) and pooled (first 32 blocks)
    for (int i = t; i < NPB * HID; i += NT) aggB[node0 * HID + i] = 0.f;
    {
        int gi = b * NT + t;
        if (gi < N_GRAPHS * HID) pooled[gi] = 0.f;
    }
    if (t == 0) cntE = 0;
    // xs rows are wave-private: thread t writes xs[t] -> row t>>5 = 2g + (c>>5)
    xs[t] = x[node0 * IN_CH + t];
    __syncthreads();   // covers cntE=0 before scan atomics (xs is wave-private)

    // lin_in: 2 nodes per thread, weights direct from L1-resident winT4
    {
        float bb = bin[c];
        float h0 = bb, h1 = bb;
        const float4* x0 = (const float4*)(xs + (2 * g + 0) * IN_CH);
        const float4* x1 = (const float4*)(xs + (2 * g + 1) * IN_CH);
#pragma unroll
        for (int k4 = 0; k4 < IN_CH / 4; ++k4) {
            float4 w = winT4[k4 * 64 + c];
            float4 a = x0[k4], d = x1[k4];
            h0 += a.x * w.x + a.y * w.y + a.z * w.z + a.w * w.w;
            h1 += d.x * w.x + d.y * w.y + d.z * w.z + d.w * w.w;
        }
        hs[(2 * g + 0) * HID + c] = h0; hG[(node0 + 2 * g + 0) * HID + c] = h0;
        hs[(2 * g + 1) * HID + c] = h1; hG[(node0 + 2 * g + 1) * HID + c] = h1;
    }

    // ynet0: 2 nodes x 5 components into LDS ys (R6-verbatim scalar weight path)
    {
        float acc[2][5] = {};
#pragma unroll 4
        for (int k = 0; k < HID; ++k) {
            float w0 = eW[0 * 4096 + k * 64 + c];
            float w1 = eW[1 * 4096 + k * 64 + c];
            float w2 = eW[2 * 4096 + k * 64 + c];
            float w3 = eW[3 * 4096 + k * 64 + c];
            float w4 = eB[k * 64 + c];
            float a0 = hs[(2 * g + 0) * HID + k];   // broadcast
            float a1 = hs[(2 * g + 1) * HID + k];
            acc[0][0] += a0 * w0; acc[0][1] += a0 * w1; acc[0][2] += a0 * w2;
            acc[0][3] += a0 * w3; acc[0][4] += a0 * w4;
            acc[1][0] += a1 * w0; acc[1][1] += a1 * w1; acc[1][2] += a1 * w2;
            acc[1][3] += a1 * w3; acc[1][4] += a1 * w4;
        }
#pragma unroll
        for (int j = 0; j < 2; ++j)
#pragma unroll
            for (int d = 0; d < 5; ++d)
                ys[(2 * g + j) * (5 * HID) + d * HID + c] = acc[j][d];
    }

    // build src-side edge buckets (this block's OUT-edges); keep in LDS + global
    for (int e = t; e < N_EDGES; e += NT) {
        int src = ei[e];
        if ((src >> 4) == b) {   // NPB == 16
            int slot = atomicAdd(&cntE, 1);
            if (slot < ECAP) {
                int2 sd = make_int2(src & 15, ei[N_EDGES + e]);
                float4 a4 = *(const float4*)(ea + 4 * (size_t)e);
                eSL[slot] = sd;           eEA[slot] = a4;
                gsd[b * ECAP + slot] = sd; gea[b * ECAP + slot] = a4;
            }
        }
    }
    __syncthreads();
    int cnt = min(cntE, ECAP);
    if (t == 0) gbcnt[b] = cnt;

    // scatter: wave g takes edges g, g+8, ... ; y read from LDS (conflict-free)
    for (int e = g; e < cnt; e += 8) {
        int2 sd = eSL[e];
        float4 a = eEA[e];
        const float* yr = ys + sd.x * (5 * HID);
        float m = a.x * yr[c] + a.y * yr[HID + c] + a.z * yr[2 * HID + c] +
                  a.w * yr[3 * HID + c] + yr[4 * HID + c];
        atomicAdd(&aggA[sd.y * HID + c], m);
    }
}

// -------- per-layer: update (rootT4 from L1 + BN/ReLU) then ynet+scatter
//          (or pool if LAST). Single block barrier (pre-scatter). --------
template <int ZERO_IN, int LAST>
__global__ __launch_bounds__(NT, 4) void klayer(
        float* __restrict__ hG,
        float* __restrict__ aggIn, float* __restrict__ aggOut,
        const float4* __restrict__ rootT4, const float* __restrict__ conv_b,
        const float* __restrict__ gam, const float* __restrict__ bet,
        const float* __restrict__ mu, const float* __restrict__ var,
        const float* __restrict__ eW, const float* __restrict__ eB,   // next layer
        const int* __restrict__ gbcnt, const int2* __restrict__ gsd,
        const float4* __restrict__ gea,
        const int* __restrict__ batch, float* __restrict__ pooled) {
    __shared__ float  hsin[NPB * HID];    //  4 KB (rows wave-private)
    __shared__ float  ys[NPB * 5 * HID];  // 20 KB
    __shared__ int2   eSL[ECAP];
    __shared__ float4 eEA[ECAP];

    const int t = threadIdx.x, b = blockIdx.x, node0 = b * NPB;
    const int c = t & 63, g = t >> 6;

    int cnt = LAST ? 0 : min(gbcnt[b], ECAP);
    // wave-private h load: no barrier needed before compute
    hsin[(2 * g + 0) * HID + c] = hG[(node0 + 2 * g + 0) * HID + c];
    hsin[(2 * g + 1) * HID + c] = hG[(node0 + 2 * g + 1) * HID + c];
    if (!LAST) {
        for (int i = t; i < cnt; i += NT) { eSL[i] = gsd[b * ECAP + i]; eEA[i] = gea[b * ECAP + i]; }
    }

    float scale = gam[c] * rsqrtf(var[c] + BN_EPS);
    float shift = bet[c] - mu[c] * scale;
    float cb = conv_b[c];

    float hnew[2];
#pragma unroll
    for (int j = 0; j < 2; ++j) {
        int ln = 2 * g + j, n = node0 + ln;
        float acc = 0.f;
        const float4* hv = (const float4*)(hsin + ln * HID);
#pragma unroll
        for (int k4 = 0; k4 < HID / 4; ++k4) {
            float4 w = rootT4[k4 * 64 + c];     // L1-resident, coalesced
            float4 h4 = hv[k4];
            acc += h4.x * w.x + h4.y * w.y + h4.z * w.z + h4.w * w.w;
        }
        float av = aggIn[n * HID + c];
        if (ZERO_IN) aggIn[n * HID + c] = 0.f;   // aggIn reused as scatter target later
        hnew[j] = fmaxf((av + acc + cb) * scale + shift, 0.f);
    }
    // overwrite own wave-private rows (all reads of them happened above, in-order)
    hsin[(2 * g + 0) * HID + c] = hnew[0];
    hsin[(2 * g + 1) * HID + c] = hnew[1];

    if (!LAST) {
        hG[(node0 + 2 * g + 0) * HID + c] = hnew[0];
        hG[(node0 + 2 * g + 1) * HID + c] = hnew[1];
        // ynet for next layer (R6-verbatim scalar weight path)
        float acc[2][5] = {};
#pragma unroll 4
        for (int k = 0; k < HID; ++k) {
            float w0 = eW[0 * 4096 + k * 64 + c];
            float w1 = eW[1 * 4096 + k * 64 + c];
            float w2 = eW[2 * 4096 + k * 64 + c];
            float w3 = eW[3 * 4096 + k * 64 + c];
            float w4 = eB[k * 64 + c];
            float a0 = hsin[(2 * g + 0) * HID + k];
            float a1 = hsin[(2 * g + 1) * HID + k];
            acc[0][0] += a0 * w0; acc[0][1] += a0 * w1; acc[0][2] += a0 * w2;
            acc[0][3] += a0 * w3; acc[0][4] += a0 * w4;
            acc[1][0] += a1 * w0; acc[1][1] += a1 * w1; acc[1][2] += a1 * w2;
            acc[1][3] += a1 * w3; acc[1][4] += a1 * w4;
        }
#pragma unroll
        for (int j = 0; j < 2; ++j)
#pragma unroll
            for (int d = 0; d < 5; ++d)
                ys[(2 * g + j) * (5 * HID) + d * HID + c] = acc[j][d];
        __syncthreads();   // ys + buckets ready for cross-wave scatter

        for (int e = g; e < cnt; e += 8) {
            int2 sd = eSL[e];
            float4 a = eEA[e];
            const float* yr = ys + sd.x * (5 * HID);
            float m = a.x * yr[c] + a.y * yr[HID + c] + a.z * yr[2 * HID + c] +
                      a.w * yr[3 * HID + c] + yr[4 * HID + c];
            atomicAdd(&aggOut[sd.y * HID + c], m);
        }
    } else {
        int n0 = node0 + 2 * g, n1 = n0 + 1;
        atomicAdd(&pooled[batch[n0] * HID + c], hnew[0]);
        atomicAdd(&pooled[batch[n1] * HID + c], hnew[1]);
    }
}

// -------- classifier: one wave per graph, shuffle reduce --------
__global__ void kclf(const float* __restrict__ pooled,
                     const float* __restrict__ W,    // [64][2]
                     const float* __restrict__ bb,
                     float* __restrict__ out) {
    int lane = threadIdx.x & 63;
    int gph = blockIdx.x * 4 + (threadIdx.x >> 6);
    float p = pooled[gph * HID + lane];
    float2 w = ((const float2*)W)[lane];
    float r0 = p * w.x, r1 = p * w.y;
#pragma unroll
    for (int off = 32; off; off >>= 1) {
        r0 += __shfl_xor(r0, off, 64);
        r1 += __shfl_xor(r1, off, 64);
    }
    if (lane == 0) {
        out[gph * 2 + 0] = r0 + bb[0];
        out[gph * 2 + 1] = r1 + bb[1];
    }
}

extern "C" void kernel_launch(void* const* d_in, const int* in_sizes, int n_in,
                              void* d_out, int out_size, void* d_ws, size_t ws_size,
                              hipStream_t stream) {
    const float* x         = (const float*)d_in[0];
    const int*   edge_index= (const int*)  d_in[1];
    const float* edge_attr = (const float*)d_in[2];
    const int*   batch     = (const int*)  d_in[3];
    const float* lin_in_W  = (const float*)d_in[4];
    const float* lin_in_b  = (const float*)d_in[5];
    const float* edge_W    = (const float*)d_in[6];   // [3,4,4096]
    const float* edge_b    = (const float*)d_in[7];   // [3,4096]
    const float* root_W    = (const float*)d_in[8];   // [3,64,64]
    const float* conv_b    = (const float*)d_in[9];   // [3,64]
    const float* bn_gamma  = (const float*)d_in[10];
    const float* bn_beta   = (const float*)d_in[11];
    const float* bn_mean   = (const float*)d_in[12];
    const float* bn_var    = (const float*)d_in[13];
    const float* clf_W     = (const float*)d_in[14];
    const float* clf_b     = (const float*)d_in[15];
    float* out = (float*)d_out;

    char* ws = (char*)d_ws;
    float*  aggA   = (float*) (ws);                                  // 2 MB
    float*  aggB   = (float*) (ws + (size_t)2 * 1024 * 1024);        // 2 MB
    float*  pooled = (float*) (ws + (size_t)4 * 1024 * 1024);        // 64 KB
    int*    gbcnt  = (int*)   (ws + (size_t)4 * 1024 * 1024 + 65536);// 2 KB
    float*  hG     = (float*) (ws + (size_t)5 * 1024 * 1024);        // 2 MB
    int2*   gsd    = (int2*)  (ws + (size_t)7 * 1024 * 1024);        // 384 KB
    float4* gea    = (float4*)(ws + (size_t)7 * 1024 * 1024 + 512 * 1024); // 768 KB
    float4* rootT4 = (float4*)(ws + (size_t)9 * 1024 * 1024);        // 48 KB
    float4* winT4  = (float4*)(ws + (size_t)9 * 1024 * 1024 + 64 * 1024);  // 8 KB

    // 1) prep: zero aggA + transpose rootW / lin_in_W
    kprep<<<512, 256, 0, stream>>>(root_W, lin_in_W, rootT4, winT4, (float4*)aggA);

    // 2) lin_in + ynet0 + bucket-build + scatter->aggA (also zeroes aggB, pooled)
    k0<<<NBLK, NT, 0, stream>>>(x, lin_in_b, winT4, edge_W, edge_b,
                                edge_index, edge_attr, hG, aggA, aggB, pooled,
                                gbcnt, gsd, gea);

    // 3) layer0 update (read+zero aggA) + ynet1 + scatter->aggB
    klayer<1, 0><<<NBLK, NT, 0, stream>>>(
        hG, aggA, aggB, rootT4, conv_b, bn_gamma, bn_beta, bn_mean, bn_var,
        edge_W + (size_t)1 * EDGE_DIM * HID * HID, edge_b + (size_t)1 * HID * HID,
        gbcnt, gsd, gea, batch, pooled);

    // 4) layer1 update (read aggB) + ynet2 + scatter->aggA (zeroed by step 3)
    klayer<0, 0><<<NBLK, NT, 0, stream>>>(
        hG, aggB, aggA, rootT4 + 1024, conv_b + (size_t)1 * HID,
        bn_gamma + HID, bn_beta + HID, bn_mean + HID, bn_var + HID,
        edge_W + (size_t)2 * EDGE_DIM * HID * HID, edge_b + (size_t)2 * HID * HID,
        gbcnt, gsd, gea, batch, pooled);

    // 5) layer2 update (read aggA) + pool
    klayer<0, 1><<<NBLK, NT, 0, stream>>>(
        hG, aggA, aggB, rootT4 + 2048, conv_b + (size_t)2 * HID,
        bn_gamma + 2 * HID, bn_beta + 2 * HID, bn_mean + 2 * HID, bn_var + 2 * HID,
        edge_W, edge_b,   // unused when LAST
        gbcnt, gsd, gea, batch, pooled);

    // 6) classifier
    kclf<<<N_GRAPHS / 4, 256, 0, stream>>>(pooled, clf_W, clf_b, out);
}

// Round 12
// 72.238 us; speedup vs baseline: 1.1409x; 1.1409x over previous
//
#include <hip/hip_runtime.h>

#define N_NODES 8192
#define N_EDGES 16384
#define IN_CH 32
#define HID 64
#define EDGE_DIM 4
#define N_LAYERS 3
#define N_GRAPHS 256
#define BN_EPS 1e-5f

#define NT 512
#define NPB 16                  // nodes per block
#define NBLK (N_NODES / NPB)    // 512 blocks
#define ECAP 96                 // out-edges per block cap (Poisson(32): P(>96) ~ e^-41)

// -------- zero a float4 span (aggA only: 2 MB) --------
__global__ void kzero(float4* __restrict__ p, int n4) {
    int i = blockIdx.x * blockDim.x + threadIdx.x;
    if (i < n4) p[i] = make_float4(0.f, 0.f, 0.f, 0.f);
}

// -------- k0: zero aggB+pooled, lin_in, ynet0 (LDS), build src-buckets, scatter->aggA --------
__global__ __launch_bounds__(NT, 4) void k0(
        const float* __restrict__ x,
        const float* __restrict__ Win, const float* __restrict__ bin,
        const float* __restrict__ eW, const float* __restrict__ eB,   // layer 0
        const int* __restrict__ ei, const float* __restrict__ ea,
        float* __restrict__ hG, float* __restrict__ aggA,
        float* __restrict__ aggB, float* __restrict__ pooled,
        int* __restrict__ gbcnt, int2* __restrict__ gsd, float4* __restrict__ gea) {
    __shared__ float  Wis[IN_CH * HID];   //  8 KB
    __shared__ float  xs[NPB * IN_CH];    //  2 KB
    __shared__ float  hs[NPB * HID];      //  4 KB
    __shared__ float  ys[NPB * 5 * HID];  // 20 KB
    __shared__ int    cntE;
    __shared__ int2   eSL[ECAP];
    __shared__ float4 eEA[ECAP];

    const int t = threadIdx.x, b = blockIdx.x, node0 = b * NPB;
    const int c = t & 63, g = t >> 6;    // wave g (0..7) owns nodes 2g, 2g+1

    // zero aggB (512 blocks x 1024 f32 = 2MB) and pooled (first 32 blocks)
    for (int i = t; i < NPB * HID; i += NT) aggB[node0 * HID + i] = 0.f;
    {
        int gi = b * NT + t;
        if (gi < N_GRAPHS * HID) pooled[gi] = 0.f;
    }
    if (t == 0) cntE = 0;
    for (int i = t; i < IN_CH * HID; i += NT) Wis[i] = Win[i];
    for (int i = t; i < NPB * IN_CH; i += NT) xs[i] = x[node0 * IN_CH + i];
    __syncthreads();

    // lin_in: 2 nodes per thread (wave-private hs rows -> no barrier needed)
    {
        float bb = bin[c];
        float h0 = bb, h1 = bb;
        const float* x0 = xs + (2 * g + 0) * IN_CH;
        const float* x1 = xs + (2 * g + 1) * IN_CH;
#pragma unroll
        for (int k = 0; k < IN_CH; ++k) {
            float wk = Wis[k * HID + c];
            h0 += x0[k] * wk; h1 += x1[k] * wk;
        }
        hs[(2 * g + 0) * HID + c] = h0; hG[(node0 + 2 * g + 0) * HID + c] = h0;
        hs[(2 * g + 1) * HID + c] = h1; hG[(node0 + 2 * g + 1) * HID + c] = h1;
    }

    // ynet0: 2 nodes x 5 components into LDS ys
    {
        float acc[2][5] = {};
#pragma unroll 4
        for (int k = 0; k < HID; ++k) {
            float w0 = eW[0 * 4096 + k * 64 + c];
            float w1 = eW[1 * 4096 + k * 64 + c];
            float w2 = eW[2 * 4096 + k * 64 + c];
            float w3 = eW[3 * 4096 + k * 64 + c];
            float w4 = eB[k * 64 + c];
            float a0 = hs[(2 * g + 0) * HID + k];   // broadcast
            float a1 = hs[(2 * g + 1) * HID + k];
            acc[0][0] += a0 * w0; acc[0][1] += a0 * w1; acc[0][2] += a0 * w2;
            acc[0][3] += a0 * w3; acc[0][4] += a0 * w4;
            acc[1][0] += a1 * w0; acc[1][1] += a1 * w1; acc[1][2] += a1 * w2;
            acc[1][3] += a1 * w3; acc[1][4] += a1 * w4;
        }
#pragma unroll
        for (int j = 0; j < 2; ++j)
#pragma unroll
            for (int d = 0; d < 5; ++d)
                ys[(2 * g + j) * (5 * HID) + d * HID + c] = acc[j][d];
    }

    // build src-side edge buckets (this block's OUT-edges); keep in LDS + global
    for (int e = t; e < N_EDGES; e += NT) {
        int src = ei[e];
        if ((src >> 4) == b) {   // NPB == 16
            int slot = atomicAdd(&cntE, 1);
            if (slot < ECAP) {
                int2 sd = make_int2(src & 15, ei[N_EDGES + e]);
                float4 a4 = *(const float4*)(ea + 4 * (size_t)e);
                eSL[slot] = sd;           eEA[slot] = a4;
                gsd[b * ECAP + slot] = sd; gea[b * ECAP + slot] = a4;
            }
        }
    }
    __syncthreads();
    int cnt = min(cntE, ECAP);
    if (t == 0) gbcnt[b] = cnt;

    // scatter: wave g takes edges g, g+8, ... ; y read from LDS (conflict-free)
    for (int e = g; e < cnt; e += 8) {
        int2 sd = eSL[e];
        float4 a = eEA[e];
        const float* yr = ys + sd.x * (5 * HID);
        float m = a.x * yr[c] + a.y * yr[HID + c] + a.z * yr[2 * HID + c] +
                  a.w * yr[3 * HID + c] + yr[4 * HID + c];
        atomicAdd(&aggA[sd.y * HID + c], m);
    }
}

// -------- per-layer: update (root+BN+ReLU) then ynet+scatter (or pool if LAST) --------
template <int ZERO_IN, int LAST>
__global__ __launch_bounds__(NT, 4) void klayer(
        float* __restrict__ hG,
        float* __restrict__ aggIn, float* __restrict__ aggOut,
        const float* __restrict__ rootW, const float* __restrict__ conv_b,
        const float* __restrict__ gam, const float* __restrict__ bet,
        const float* __restrict__ mu, const float* __restrict__ var,
        const float* __restrict__ eW, const float* __restrict__ eB,   // next layer
        const int* __restrict__ gbcnt, const int2* __restrict__ gsd,
        const float4* __restrict__ gea,
        const int* __restrict__ batch, float* __restrict__ pooled) {
    __shared__ float  Ws[HID * HID];      // 16 KB
    __shared__ float  hsin[NPB * HID];    //  4 KB
    __shared__ float  ys[NPB * 5 * HID];  // 20 KB
    __shared__ int2   eSL[ECAP];
    __shared__ float4 eEA[ECAP];

    const int t = threadIdx.x, b = blockIdx.x, node0 = b * NPB;
    const int c = t & 63, g = t >> 6;

    int cnt = LAST ? 0 : min(gbcnt[b], ECAP);
    for (int i = t; i < HID * HID; i += NT) Ws[i] = rootW[i];
    for (int i = t; i < NPB * HID; i += NT) hsin[i] = hG[node0 * HID + i];
    if (!LAST) {
        for (int i = t; i < cnt; i += NT) { eSL[i] = gsd[b * ECAP + i]; eEA[i] = gea[b * ECAP + i]; }
    }
    __syncthreads();

    float scale = gam[c] * rsqrtf(var[c] + BN_EPS);
    float shift = bet[c] - mu[c] * scale;
    float cb = conv_b[c];

    float hnew[2];
#pragma unroll
    for (int j = 0; j < 2; ++j) {
        int ln = 2 * g + j, n = node0 + ln;
        float acc = 0.f;
        const float4* hv = (const float4*)(hsin + ln * HID);
#pragma unroll
        for (int k4 = 0; k4 < HID / 4; ++k4) {
            float4 h4 = hv[k4];
            acc += h4.x * Ws[(4 * k4 + 0) * 64 + c] + h4.y * Ws[(4 * k4 + 1) * 64 + c] +
                   h4.z * Ws[(4 * k4 + 2) * 64 + c] + h4.w * Ws[(4 * k4 + 3) * 64 + c];
        }
        float av = aggIn[n * HID + c];
        if (ZERO_IN) aggIn[n * HID + c] = 0.f;   // aggIn reused as scatter target later
        hnew[j] = fmaxf((av + acc + cb) * scale + shift, 0.f);
    }
    // overwrite own wave-private rows (all reads of them happened above, in-order)
    hsin[(2 * g + 0) * HID + c] = hnew[0];
    hsin[(2 * g + 1) * HID + c] = hnew[1];

    if (!LAST) {
        hG[(node0 + 2 * g + 0) * HID + c] = hnew[0];
        hG[(node0 + 2 * g + 1) * HID + c] = hnew[1];
        // ynet for next layer
        float acc[2][5] = {};
#pragma unroll 4
        for (int k = 0; k < HID; ++k) {
            float w0 = eW[0 * 4096 + k * 64 + c];
            float w1 = eW[1 * 4096 + k * 64 + c];
            float w2 = eW[2 * 4096 + k * 64 + c];
            float w3 = eW[3 * 4096 + k * 64 + c];
            float w4 = eB[k * 64 + c];
            float a0 = hsin[(2 * g + 0) * HID + k];
            float a1 = hsin[(2 * g + 1) * HID + k];
            acc[0][0] += a0 * w0; acc[0][1] += a0 * w1; acc[0][2] += a0 * w2;
            acc[0][3] += a0 * w3; acc[0][4] += a0 * w4;
            acc[1][0] += a1 * w0; acc[1][1] += a1 * w1; acc[1][2] += a1 * w2;
            acc[1][3] += a1 * w3; acc[1][4] += a1 * w4;
        }
#pragma unroll
        for (int j = 0; j < 2; ++j)
#pragma unroll
            for (int d = 0; d < 5; ++d)
                ys[(2 * g + j) * (5 * HID) + d * HID + c] = acc[j][d];
        __syncthreads();

        for (int e = g; e < cnt; e += 8) {
            int2 sd = eSL[e];
            float4 a = eEA[e];
            const float* yr = ys + sd.x * (5 * HID);
            float m = a.x * yr[c] + a.y * yr[HID + c] + a.z * yr[2 * HID + c] +
                      a.w * yr[3 * HID + c] + yr[4 * HID + c];
            atomicAdd(&aggOut[sd.y * HID + c], m);
        }
    } else {
        int n0 = node0 + 2 * g, n1 = n0 + 1;
        atomicAdd(&pooled[batch[n0] * HID + c], hnew[0]);
        atomicAdd(&pooled[batch[n1] * HID + c], hnew[1]);
    }
}

// -------- classifier: one wave per graph, shuffle reduce --------
__global__ void kclf(const float* __restrict__ pooled,
                     const float* __restrict__ W,    // [64][2]
                     const float* __restrict__ bb,
                     float* __restrict__ out) {
    int lane = threadIdx.x & 63;
    int gph = blockIdx.x * 4 + (threadIdx.x >> 6);
    float p = pooled[gph * HID + lane];
    float2 w = ((const float2*)W)[lane];
    float r0 = p * w.x, r1 = p * w.y;
#pragma unroll
    for (int off = 32; off; off >>= 1) {
        r0 += __shfl_xor(r0, off, 64);
        r1 += __shfl_xor(r1, off, 64);
    }
    if (lane == 0) {
        out[gph * 2 + 0] = r0 + bb[0];
        out[gph * 2 + 1] = r1 + bb[1];
    }
}

extern "C" void kernel_launch(void* const* d_in, const int* in_sizes, int n_in,
                              void* d_out, int out_size, void* d_ws, size_t ws_size,
                              hipStream_t stream) {
    const float* x         = (const float*)d_in[0];
    const int*   edge_index= (const int*)  d_in[1];
    const float* edge_attr = (const float*)d_in[2];
    const int*   batch     = (const int*)  d_in[3];
    const float* lin_in_W  = (const float*)d_in[4];
    const float* lin_in_b  = (const float*)d_in[5];
    const float* edge_W    = (const float*)d_in[6];   // [3,4,4096]
    const float* edge_b    = (const float*)d_in[7];   // [3,4096]
    const float* root_W    = (const float*)d_in[8];   // [3,64,64]
    const float* conv_b    = (const float*)d_in[9];   // [3,64]
    const float* bn_gamma  = (const float*)d_in[10];
    const float* bn_beta   = (const float*)d_in[11];
    const float* bn_mean   = (const float*)d_in[12];
    const float* bn_var    = (const float*)d_in[13];
    const float* clf_W     = (const float*)d_in[14];
    const float* clf_b     = (const float*)d_in[15];
    float* out = (float*)d_out;

    char* ws = (char*)d_ws;
    float*  aggA   = (float*) (ws);                                  // 2 MB
    float*  aggB   = (float*) (ws + (size_t)2 * 1024 * 1024);        // 2 MB
    float*  pooled = (float*) (ws + (size_t)4 * 1024 * 1024);        // 64 KB
    int*    gbcnt  = (int*)   (ws + (size_t)4 * 1024 * 1024 + 65536);// 2 KB
    float*  hG     = (float*) (ws + (size_t)5 * 1024 * 1024);        // 2 MB
    int2*   gsd    = (int2*)  (ws + (size_t)7 * 1024 * 1024);        // 384 KB
    float4* gea    = (float4*)(ws + (size_t)7 * 1024 * 1024 + 512 * 1024); // 768 KB

    // 1) zero aggA (k0's scatter target)
    const int n4 = (2 * 1024 * 1024) / 16;
    kzero<<<(n4 + 255) / 256, 256, 0, stream>>>((float4*)aggA, n4);

    // 2) lin_in + ynet0 + bucket-build + scatter->aggA (also zeroes aggB, pooled)
    k0<<<NBLK, NT, 0, stream>>>(x, lin_in_W, lin_in_b, edge_W, edge_b,
                                edge_index, edge_attr, hG, aggA, aggB, pooled,
                                gbcnt, gsd, gea);

    // 3) layer0 update (read+zero aggA) + ynet1 + scatter->aggB
    klayer<1, 0><<<NBLK, NT, 0, stream>>>(
        hG, aggA, aggB, root_W, conv_b, bn_gamma, bn_beta, bn_mean, bn_var,
        edge_W + (size_t)1 * EDGE_DIM * HID * HID, edge_b + (size_t)1 * HID * HID,
        gbcnt, gsd, gea, batch, pooled);

    // 4) layer1 update (read aggB) + ynet2 + scatter->aggA (zeroed by step 3)
    klayer<0, 0><<<NBLK, NT, 0, stream>>>(
        hG, aggB, aggA, root_W + (size_t)1 * HID * HID, conv_b + (size_t)1 * HID,
        bn_gamma + HID, bn_beta + HID, bn_mean + HID, bn_var + HID,
        edge_W + (size_t)2 * EDGE_DIM * HID * HID, edge_b + (size_t)2 * HID * HID,
        gbcnt, gsd, gea, batch, pooled);

    // 5) layer2 update (read aggA) + pool
    klayer<0, 1><<<NBLK, NT, 0, stream>>>(
        hG, aggA, aggB, root_W + (size_t)2 * HID * HID, conv_b + (size_t)2 * HID,
        bn_gamma + 2 * HID, bn_beta + 2 * HID, bn_mean + 2 * HID, bn_var + 2 * HID,
        edge_W, edge_b,   // unused when LAST
        gbcnt, gsd, gea, batch, pooled);

    // 6) classifier
    kclf<<<N_GRAPHS / 4, 256, 0, stream>>>(pooled, clf_W, clf_b, out);
}